// Round 13
// baseline (4968.546 us; speedup 1.0000x reference)
//
#include <hip/hip_runtime.h>

// ---------------- problem constants ----------------
#define HND    233
#define NL     6
#define GPL    15             // WGs per layer
#define UPW    16             // units per WG (15*16 = 240 >= 233)
#define ROWS   64             // gate rows per WG
#define TSTEPS 16
#define FSTEPS 96
#define NSLOT  (TSTEPS*FSTEPS)
#define CDIM   12
#define G4H    (4*HND)        // 932
#define HP     240            // h-section offset in vin row
#define VINW   496            // vin row: [x 240 | h 240 | pad 16]
#define NTICK  (6*95+15+1)    // 586 wavefront ticks (critical-path optimal)
#define NHEAD  3
#define BLOCK  256
#define NWORD  234            // u64 words per stream (117 x + 117 h)
#define RLW    240            // u64 per mailbox ring cell [x 117+pad | h 117+pad]
#define MBC    (16*RLW)       // u64 per consumer mailbox (ring of 16)
#define NMB    (NL*GPL)       // 90 consumer mailboxes
#define H5W    120            // u64 per hout5 row (head path, write-once)
#define AG     __HIP_MEMORY_SCOPE_AGENT
#define SENT   0x7FBADBADu    // NaN pattern: unreachable by real data
#define SENT64 0x7FBADBAD7FBADBADull
#define PLIM   (1L << 18)     // poll bail (loud NaN, no hang)

typedef unsigned long long u64;

__device__ __forceinline__ float sigf(float x) { return 1.f / (1.f + expf(-x)); }
__device__ __forceinline__ bool rdy(u64 v) {
  return ((unsigned)v != SENT) && ((unsigned)(v >> 32) != SENT);
}

// Active (f,t) streams at tick m: t = m - 6f in [0,15]; ns <= 3.
__device__ __forceinline__ int build(int m, int* fl, int* tl) {
  const int fh0 = m / 6;
  const int f_hi = (fh0 > 95) ? 95 : fh0;
  const int f_lo = (m < 10) ? 0 : (m - 10) / 6;
  #pragma unroll
  for (int k = 0; k < 3; ++k) { fl[k] = f_lo + k; tl[k] = m - 6 * (f_lo + k); }
  return f_hi - f_lo + 1;
}

// Re-poison all mailbox + hout5 words to the sentinel.
__global__ void init_kernel(u64* __restrict__ buf, size_t n) {
  size_t i = (size_t)blockIdx.x * blockDim.x + threadIdx.x;
  size_t st = (size_t)gridDim.x * blockDim.x;
  for (size_t k = i; k < n; k += st) buf[k] = SENT64;
}

// grid: NL*GPL layer WGs + NHEAD head WGs, 256 threads.
// PRIVATE-MAILBOX protocol: producers replicate relaxed data stores into each
// consumer WG's own mailbox (ring of 16, ring index = t of the source slot);
// consumers poll ONLY their private lines (<=16 pollers/line -> no MALL line
// contention), then clear consumed words to SENT (rewrite is >=5 ticks away;
// the clear drains at the next barrier's vmcnt(0)). No flags, no counters.
__global__ void __launch_bounds__(BLOCK, 1) lstm_pipe(
    const float* __restrict__ X,
    const float* __restrict__ Wih0, const float* __restrict__ Wih,
    const float* __restrict__ Whh,  const float* __restrict__ bih,
    const float* __restrict__ bhh,  const float* __restrict__ Wl,
    const float* __restrict__ bl,   float* __restrict__ out,
    u64* __restrict__ mbu, u64* __restrict__ h5u) {
  __shared__ float vin[3][VINW];        // stream buffers (list-position keyed)
  __shared__ float part[3][BLOCK];
  __shared__ float bias[ROWS];
  __shared__ float foldb[ROWS];         // l0: Wih0 @ bl (f>=1 only)
  __shared__ float cst[3][UPW];         // c-state, keyed f%3
  __shared__ float wih0s[ROWS][CDIM];   // l0: raw Wih0 rows (f==0 correction)
  __shared__ float xs[TSTEPS][CDIM];    // l0: f==0 seed = X[t][95][:]
  __shared__ float wlh[CDIM][HP];       // Wl padded (l0 fold + head dot)

  const int tid = threadIdx.x;
  const int bid = blockIdx.x;

  if (bid >= NL * GPL) {
    // ---------------- head WGs: out[t][f][:] = Wl.h5(f,t)+bl, f%3==hid ----
    const int hid = bid - NL * GPL;
    for (int i = tid; i < CDIM * HP; i += BLOCK) {
      int rr = i / HP, k = i % HP;
      ((float*)wlh)[i] = (k < HND) ? Wl[rr * HND + k] : 0.f;
    }
    for (int i = tid; i < VINW; i += BLOCK) vin[0][i] = 0.f;
    __syncthreads();
    for (int f = hid; f < FSTEPS; f += NHEAD) {
      for (int t = 0; t < TSTEPS; ++t) {
        if (tid < 117) {
          const u64* src = h5u + (size_t)(16 * f + t) * H5W + tid;
          u64 v; long gd = 0;
          for (;;) {
            v = __hip_atomic_load(src, __ATOMIC_RELAXED, AG);
            if (rdy(v)) break;
            if (++gd > PLIM) break;
            if (gd > 4) __builtin_amdgcn_s_sleep(1);
          }
          *(u64*)&vin[0][2 * tid] = v;
        }
        __syncthreads();
        if (tid < 48) {
          int rr = tid >> 2, q = tid & 3;
          const float4* wr = (const float4*)&wlh[rr][0];
          const float4* hv = (const float4*)&vin[0][0];
          float a = 0.f;
          #pragma unroll
          for (int c = 0; c < 15; ++c) {
            float4 x0 = wr[q * 15 + c], y0 = hv[q * 15 + c];
            a = fmaf(x0.w, y0.w, fmaf(x0.z, y0.z, fmaf(x0.y, y0.y, fmaf(x0.x, y0.x, a))));
          }
          a += __shfl_xor(a, 1);
          a += __shfl_xor(a, 2);
          if (q == 0) out[((size_t)t * FSTEPS + f) * CDIM + rr] = a + bl[rr];
        }
        __syncthreads();
      }
    }
    return;
  }

  // ---------------- layer workgroup ----------------
  const int l = bid / GPL, g = bid % GPL;
  const int j0 = g * UPW;
  const int U = min(UPW, HND - j0);            // last WG: 9 units
  const int r = tid & 63, q = tid >> 6;        // matvec row / k-quarter
  const int u = r >> 2, gt = r & 3;
  const int grow = gt * HND + j0 + u;
  const bool rowok = (u < U);
  u64* mbOwn = mbu + (size_t)(l * GPL + g) * MBC;

  // ---- small LDS tables
  if (l == 0) {
    for (int i = tid; i < CDIM * HP; i += BLOCK) {
      int r2 = i / HP, k = i % HP;
      ((float*)wlh)[i] = (k < HND) ? Wl[r2 * HND + k] : 0.f;
    }
    for (int i = tid; i < ROWS * CDIM; i += BLOCK) {
      int r2 = i / CDIM, c = i % CDIM;
      int uu = r2 >> 2, g2 = r2 & 3;
      wih0s[r2][c] = (uu < U) ? Wih0[(g2 * HND + j0 + uu) * CDIM + c] : 0.f;
    }
    for (int i = tid; i < TSTEPS * CDIM; i += BLOCK)
      xs[i / CDIM][i % CDIM] = X[((size_t)(i / CDIM) * 96 + 95) * CDIM + (i % CDIM)];
  }
  for (int i = tid; i < 3 * VINW; i += BLOCK) ((float*)vin)[i] = 0.f;
  __syncthreads();

  // ---- weights into registers (124-float slice; statically indexed)
  // row layout: [x-weights 240 | Whh 240 | pad]; l0 x-weights = Wih0 @ Wl.
  float4 w4[31];
  const float* wihl = Wih + (size_t)(l - 1) * G4H * HND;
  const float* whhl = Whh + (size_t)l * G4H * HND;
  #pragma unroll
  for (int j = 0; j < 31; ++j) {
    float e[4];
    #pragma unroll
    for (int ee = 0; ee < 4; ++ee) {
      const int idx = (q * 31 + j) * 4 + ee;
      float v = 0.f;
      if (rowok) {
        if (idx < HND) {
          if (l == 0) {
            float acc = 0.f;
            #pragma unroll
            for (int c = 0; c < CDIM; ++c) acc = fmaf(wih0s[r][c], wlh[c][idx], acc);
            v = acc;
          } else {
            v = wihl[(size_t)grow * HND + idx];
          }
        } else if (idx >= HP && idx < HP + HND) {
          v = whhl[(size_t)grow * HND + (idx - HP)];
        }
      }
      e[ee] = v;
    }
    w4[j] = make_float4(e[0], e[1], e[2], e[3]);
  }
  if (tid < ROWS) {
    float b = 0.f, fb = 0.f;
    if ((tid >> 2) < U) {
      const int gr2 = (tid & 3) * HND + j0 + (tid >> 2);
      b = bih[l * G4H + gr2] + bhh[l * G4H + gr2];
      if (l == 0) {   // Wih0 @ bl: folded-token path only (f>=1)
        #pragma unroll
        for (int c = 0; c < CDIM; ++c) fb = fmaf(wih0s[tid][c], bl[c], fb);
      }
    }
    bias[tid] = b;
    foldb[tid] = fb;
  }
  __syncthreads();

  int fl[3], tl[3];

  for (int m = 0; m < NTICK; ++m) {
    const int ns = build(m, fl, tl);

    // ---- STAGE: poll PRIVATE mailbox words (<=3 per thread)
    u64 *s0 = nullptr, *s1 = nullptr, *s2 = nullptr;
    u64 *d0 = nullptr, *d1 = nullptr, *d2 = nullptr;

    auto setup = [&](int w, u64*& sp, u64*& dp) {
      const int k = w / NWORD;
      if (k >= ns) return;
      const int f = fl[k], t = tl[k];
      const int o = w - k * NWORD;
      if (o < 117) {                       // x-section word, ring = t
        float* dst = &vin[k][2 * o];
        if (l == 0 && f == 0) { dst[0] = 0.f; dst[1] = 0.f; return; }
        sp = mbOwn + (size_t)t * RLW + o;
        dp = (u64*)dst;
      } else {                             // h-section word, ring = t-1
        const int jj = o - 117;
        float* dst = &vin[k][HP + 2 * jj];
        if (t == 0) { dst[0] = 0.f; dst[1] = 0.f; return; }
        if ((jj >> 3) == g) return;        // own slice: cell wrote LDS directly
        sp = mbOwn + (size_t)(t - 1) * RLW + 117 + jj;
        dp = (u64*)dst;
      }
    };
    setup(tid, s0, d0);
    setup(tid + 256, s1, d1);
    if (tid + 512 < 3 * NWORD) setup(tid + 512, s2, d2);
    u64 *q0 = s0, *q1 = s1, *q2 = s2;     // keep for the post-read clear

    long gd = 0;
    while (s0 || s1 || s2) {
      if (s0) { u64 v = __hip_atomic_load(s0, __ATOMIC_RELAXED, AG);
                if (rdy(v)) { *d0 = v; s0 = nullptr; } }
      if (s1) { u64 v = __hip_atomic_load(s1, __ATOMIC_RELAXED, AG);
                if (rdy(v)) { *d1 = v; s1 = nullptr; } }
      if (s2) { u64 v = __hip_atomic_load(s2, __ATOMIC_RELAXED, AG);
                if (rdy(v)) { *d2 = v; s2 = nullptr; } }
      if (++gd > PLIM) break;              // bail loudly (NaN), no hang
      if (gd > 8) __builtin_amdgcn_s_sleep(1);
    }
    // clear consumed ring cells (rewrite >=5 ticks away; drained at barrier)
    if (q0) __hip_atomic_store(q0, SENT64, __ATOMIC_RELAXED, AG);
    if (q1) __hip_atomic_store(q1, SENT64, __ATOMIC_RELAXED, AG);
    if (q2) __hip_atomic_store(q2, SENT64, __ATOMIC_RELAXED, AG);
    __syncthreads();

    // ---- MATVEC: active streams only; weights in regs, vin broadcast reads
    {
      const float4* va = (const float4*)&vin[0][0];
      float a = 0.f;
      #pragma unroll
      for (int j = 0; j < 31; ++j) {
        const float4 wv = w4[j];
        const float4 y = va[q * 31 + j];
        a = fmaf(wv.x, y.x, fmaf(wv.y, y.y, fmaf(wv.z, y.z, fmaf(wv.w, y.w, a))));
      }
      part[0][tid] = a;
    }
    if (ns > 1) {
      const float4* vb = (const float4*)&vin[1][0];
      float a = 0.f;
      #pragma unroll
      for (int j = 0; j < 31; ++j) {
        const float4 wv = w4[j];
        const float4 y = vb[q * 31 + j];
        a = fmaf(wv.x, y.x, fmaf(wv.y, y.y, fmaf(wv.z, y.z, fmaf(wv.w, y.w, a))));
      }
      part[1][tid] = a;
    }
    if (ns > 2) {
      const float4* vc = (const float4*)&vin[2][0];
      float a = 0.f;
      #pragma unroll
      for (int j = 0; j < 31; ++j) {
        const float4 wv = w4[j];
        const float4 y = vc[q * 31 + j];
        a = fmaf(wv.x, y.x, fmaf(wv.y, y.y, fmaf(wv.z, y.z, fmaf(wv.w, y.w, a))));
      }
      part[2][tid] = a;
    }
    __syncthreads();

    // ---- CELL (wave-0 lanes 0..47: stream k=tid>>4, unit uu=tid&15)
    float hn = 0.f;
    const int kc = tid >> 4, uu = tid & 15;
    if (tid < 48 && kc < ns) {
      const int f = fl[kc], t = tl[kc], b3 = f % 3;
      float gg[4];
      #pragma unroll
      for (int g2 = 0; g2 < 4; ++g2) {
        const int rr = 4 * uu + g2;
        float s = part[kc][rr] + part[kc][rr + 64] + part[kc][rr + 128] +
                  part[kc][rr + 192] + bias[rr];
        if (l == 0) {
          if (f == 0) {                    // x = raw 12-dim seed
            #pragma unroll
            for (int c = 0; c < CDIM; ++c) s = fmaf(wih0s[rr][c], xs[t][c], s);
          } else {
            s += foldb[rr];                // folded Wih0 @ bl
          }
        }
        gg[g2] = s;
      }
      if (uu < U) {
        const float cp = (t == 0) ? 0.f : cst[b3][uu];
        const float cn = sigf(gg[1]) * cp + sigf(gg[0]) * tanhf(gg[2]);
        hn = sigf(gg[3]) * tanhf(cn);
        cst[b3][uu] = cn;
        if (t < 15) {                      // own slice straight into next vin
          const int fln = ((m + 1) < 10) ? 0 : (m + 1 - 10) / 6;
          vin[f - fln][HP + j0 + uu] = hn;
        }
      }
    }

    // ---- PUBLISH: wave 0, replicated stores into private mailboxes.
    // jobs = stream k (3) x dest d (30) x pair j (8); ~12 stores/lane.
    if (tid < 64) {
      #pragma unroll
      for (int base = 0; base < 768; base += 64) {
        const int idx = base + tid;
        const int k = idx / 240;
        const int rem = idx - k * 240;
        const int d = rem >> 3, j = rem & 7;
        const float lo = __shfl(hn, 16 * k + 2 * j);       // uniform-active
        const float hi = __shfl(hn, 16 * k + 2 * j + 1);
        if (idx >= 720 || k >= ns) continue;
        const int pu = j0 + 2 * j;
        if (pu >= HND) continue;
        const int f = fl[k], t = tl[k];
        const u64 pv = ((u64)__float_as_uint(hi) << 32) | (u64)__float_as_uint(lo);
        u64* dst;
        if (d < 15) {                      // x-section of layer above (l5->l0)
          const int lup = (l == 5) ? 0 : (l + 1);
          dst = mbu + (size_t)(lup * GPL + d) * MBC + (size_t)t * RLW + (j0 >> 1) + j;
        } else if (d < 29) {               // h-section of same-layer peers
          int dd = d - 15; dd += (dd >= g);
          dst = mbu + (size_t)(l * GPL + dd) * MBC + (size_t)t * RLW + 117 + (j0 >> 1) + j;
        } else {                           // head path (write-once array)
          if (l != 5) continue;
          dst = h5u + (size_t)(16 * f + t) * H5W + (j0 >> 1) + j;
        }
        __hip_atomic_store(dst, pv, __ATOMIC_RELAXED, AG);
      }
    }
    // no barrier here: stage(m+1) skips own-slice words; matvec(m+1) reads are
    // ordered behind the next stage barrier, which wave 0 reaches after cell.
  }
}

extern "C" void kernel_launch(void* const* d_in, const int* in_sizes, int n_in,
                              void* d_out, int out_size, void* d_ws, size_t ws_size,
                              hipStream_t stream) {
  const float* X    = (const float*)d_in[0];
  const float* Wih0 = (const float*)d_in[1];
  const float* Wih  = (const float*)d_in[2];
  const float* Whh  = (const float*)d_in[3];
  const float* bih  = (const float*)d_in[4];
  const float* bhh  = (const float*)d_in[5];
  const float* Wl   = (const float*)d_in[6];
  const float* bl   = (const float*)d_in[7];

  // workspace: mailboxes [90][16][240]u64 (2.77MB) + hout5 [1536][120]u64 (1.47MB)
  u64* mbu = (u64*)d_ws;
  u64* h5u = mbu + (size_t)NMB * MBC;
  const size_t nwords = (size_t)NMB * MBC + (size_t)NSLOT * H5W;

  init_kernel<<<1024, 256, 0, stream>>>(mbu, nwords);
  lstm_pipe<<<NL * GPL + NHEAD, BLOCK, 0, stream>>>(
      X, Wih0, Wih, Whh, bih, bhh, Wl, bl, (float*)d_out, mbu, h5u);
}